// Round 13
// baseline (199.911 us; speedup 1.0000x reference)
//
#include <hip/hip_runtime.h>
#include <math.h>

#define BATCH 4096
#define NC    8192
#define DIM   512
#define KEXP  5
#define NCAND 10

using bf16x8 = __attribute__((ext_vector_type(8))) short;
using f32x4  = __attribute__((ext_vector_type(4))) float;
typedef unsigned long long u64;

__device__ unsigned short g_zbf[BATCH * DIM];   // 4 MB bf16(z)
__device__ unsigned short g_cbf[NC * DIM];      // 8 MB bf16(centers)
__device__ float g_z2[BATCH];
__device__ float g_c2[NC];

__device__ __forceinline__ unsigned short rtne_bf16(float f) {
  unsigned u = __float_as_uint(f);
  u += 0x7FFFu + ((u >> 16) & 1u);
  return (unsigned short)(u >> 16);
}

__device__ __forceinline__ void gload16(const void* g, void* l) {
  __builtin_amdgcn_global_load_lds(
      (const __attribute__((address_space(1))) void*)g,
      (__attribute__((address_space(3))) void*)l, 16, 0, 0);
}

// ---------------------------------------------------------------------------
// Kernel 0: f32 -> bf16 (RTN) conversion FUSED with f64 row-norms.
// ---------------------------------------------------------------------------
__global__ __launch_bounds__(256) void convert_kernel(const float* __restrict__ z,
                                                      const float* __restrict__ c) {
  const size_t i = ((size_t)blockIdx.x * 256 + threadIdx.x) * 8;
  const size_t zn = (size_t)BATCH * DIM;
  const float* src;
  unsigned short* dst;
  float* ndst;
  size_t off;
  if (i < zn) { src = z; dst = g_zbf; ndst = g_z2; off = i; }
  else        { src = c; dst = g_cbf; ndst = g_c2; off = i - zn; }
  float4 a = *(const float4*)(src + off);
  float4 b = *(const float4*)(src + off + 4);
  uint4 o;
  o.x = (unsigned)rtne_bf16(a.x) | ((unsigned)rtne_bf16(a.y) << 16);
  o.y = (unsigned)rtne_bf16(a.z) | ((unsigned)rtne_bf16(a.w) << 16);
  o.z = (unsigned)rtne_bf16(b.x) | ((unsigned)rtne_bf16(b.y) << 16);
  o.w = (unsigned)rtne_bf16(b.z) | ((unsigned)rtne_bf16(b.w) << 16);
  *(uint4*)(dst + off) = o;

  double s = (double)a.x * a.x + (double)a.y * a.y + (double)a.z * a.z + (double)a.w * a.w +
             (double)b.x * b.x + (double)b.y * b.y + (double)b.z * b.z + (double)b.w * b.w;
#pragma unroll
  for (int sh = 32; sh > 0; sh >>= 1) s += __shfl_xor(s, sh);
  if ((threadIdx.x & 63) == 0) ndst[off / DIM] = (float)s;
}

// ---------------------------------------------------------------------------
// Kernel 2: attractions GEMM, 256x256 tile, BK=64, 8 waves, SINGLE-buffered
// 64 KB LDS -> 2 blocks/CU. Staging traffic = 256 MB (half of 128^2 tiling);
// the co-resident block's waves cover barrier drains (gemm_dots evidence:
// multi-block TLP streams at 6.2 TB/s with plain __syncthreads).
// Fragments / swizzle / epilogue identical to validated round-9 kernel.
// ---------------------------------------------------------------------------
#define BMT 256
#define BNT 256
#define BKT 64

__global__ __launch_bounds__(512) void attr_bf16(const float* __restrict__ mus,
                                                 float* __restrict__ att) {
  __shared__ __align__(16) unsigned short Ab[BMT * BKT];  // 32 KB
  __shared__ __align__(16) unsigned short Bb[BMT * BKT];  // 32 KB

  const int tid  = threadIdx.x;
  const int lane = tid & 63;
  const int wv   = tid >> 6;        // 0..7
  const int wm   = wv >> 2;         // 0..1  (M half: 128 rows)
  const int wn   = wv & 3;          // 0..3  (N quarter: 64 cols)
  const int l15  = lane & 15;
  const int q    = lane >> 4;       // 0..3

  // XCD strip: 2 tile-rows x 32 tile-cols per XCD, column-major walk
  const int flat = blockIdx.x;      // 512 blocks
  const int xcd  = flat & 7;
  const int tt   = flat >> 3;       // 0..63
  const int row0 = (xcd * 2 + (tt & 1)) * BMT;
  const int col0 = (tt >> 1) * BNT;

  const unsigned short* Ag = g_zbf + (size_t)row0 * DIM;
  const unsigned short* Bg = g_cbf + (size_t)col0 * DIM;

  const int crow = lane >> 3;            // 0..7
  const int sg   = (lane & 7) ^ crow;    // pre-swizzled source granule

  f32x4 acc[8][4] = {};

  for (int s = 0; s < 8; ++s) {
    // ---- stage tile s (64 KB, 8 gload16/wave) ----
    {
      const int k0_ = s * BKT;
#pragma unroll
      for (int inst = 0; inst < 4; ++inst) {
        const int r_ = wv * 32 + inst * 8 + crow;
        gload16(Ag + (size_t)r_ * DIM + k0_ + sg * 8, &Ab[(wv * 32 + inst * 8) * 64]);
        gload16(Bg + (size_t)r_ * DIM + k0_ + sg * 8, &Bb[(wv * 32 + inst * 8) * 64]);
      }
    }
    __syncthreads();

    // ---- compute (2 kk-steps of K=32, 64 MFMA/wave) ----
#pragma unroll
    for (int kk = 0; kk < 2; ++kk) {
      const int gq = (kk * 4 + q) ^ (lane & 7);
      bf16x8 fa[8], fb[4];
#pragma unroll
      for (int i = 0; i < 8; ++i) {
        const int r = wm * 128 + i * 16 + l15;
        fa[i] = *(const bf16x8*)(&Ab[r * 64 + gq * 8]);
      }
#pragma unroll
      for (int j = 0; j < 4; ++j) {
        const int r = wn * 64 + j * 16 + l15;
        fb[j] = *(const bf16x8*)(&Bb[r * 64 + gq * 8]);
      }
      __builtin_amdgcn_s_setprio(1);
#pragma unroll
      for (int i = 0; i < 8; ++i)
#pragma unroll
        for (int j = 0; j < 4; ++j)
          acc[i][j] = __builtin_amdgcn_mfma_f32_16x16x32_bf16(fb[j], fa[i], acc[i][j], 0, 0, 0);
      __builtin_amdgcn_s_setprio(0);
    }
    __syncthreads();
  }

  // epilogue: validated mapping + dwordx4 stores
#pragma unroll
  for (int i = 0; i < 8; ++i) {
    const int ar = row0 + wm * 128 + i * 16 + l15;
    const float zz = g_z2[ar];
    float* dst = att + (size_t)ar * NC;
#pragma unroll
    for (int j = 0; j < 4; ++j) {
      const int gc0 = col0 + wn * 64 + j * 16 + q * 4;
      const float4 cc = *(const float4*)&g_c2[gc0];
      const float4 mu = *(const float4*)&mus[gc0];
      const float ccv[4] = {cc.x, cc.y, cc.z, cc.w};
      const float muv[4] = {mu.x, mu.y, mu.z, mu.w};
      float o[4];
#pragma unroll
      for (int r = 0; r < 4; ++r) {
        float ttv = __fadd_rn(zz, ccv[r]);
        float sq  = __fsub_rn(ttv, __fmul_rn(2.0f, acc[i][j][r]));
        float d   = sqrtf(fmaxf(sq, 0.0f));
        float den = __fadd_rn(__fmul_rn(d, d), 1e-6f);
        o[r] = __fdiv_rn(muv[r], den);
      }
      *(float4*)(dst + gc0) = *(const float4*)o;
    }
  }
}

// ---------------------------------------------------------------------------
// Kernel 3: wave-per-row top-NCAND via packed-key pop-lists (unchanged).
// ---------------------------------------------------------------------------
__global__ __launch_bounds__(256, 4) void topk_kernel(const float* __restrict__ att,
                                                      const float* __restrict__ z,
                                                      const float* __restrict__ centers,
                                                      const float* __restrict__ mus,
                                                      float* __restrict__ out) {
  __shared__ int selLds[4][16];
  const int lane = threadIdx.x & 63;
  const int wv   = threadIdx.x >> 6;
  const int row  = blockIdx.x * 4 + wv;
  const float4* arow4 = (const float4*)(att + (size_t)row * NC);

  u64 k[8][4];
#pragma unroll
  for (int c = 0; c < 8; ++c) {
#pragma unroll
    for (int j = 0; j < 4; ++j) k[c][j] = 0ull;
#pragma unroll
    for (int qq = 0; qq < 4; ++qq) {
      float4 v4 = arow4[c * 256 + qq * 64 + lane];
      const unsigned ib = (unsigned)(c * 1024 + qq * 256 + lane * 4);
      const float vv[4] = {v4.x, v4.y, v4.z, v4.w};
#pragma unroll
      for (int e = 0; e < 4; ++e) {
        u64 nk = ((u64)__float_as_uint(vv[e]) << 32) | (u64)(0xFFFFFFFFu - (ib + e));
        bool g0 = nk > k[c][0], g1 = nk > k[c][1], g2 = nk > k[c][2], g3 = nk > k[c][3];
        u64 t0 = k[c][0], t1 = k[c][1], t2 = k[c][2];
        k[c][0] = g0 ? nk : k[c][0];
        k[c][1] = g0 ? t0 : (g1 ? nk : k[c][1]);
        k[c][2] = g1 ? t1 : (g2 ? nk : k[c][2]);
        k[c][3] = g2 ? t2 : (g3 ? nk : k[c][3]);
      }
    }
  }

  for (int it = 0; it < NCAND; ++it) {
    u64 b = k[0][0];
#pragma unroll
    for (int c = 1; c < 8; ++c) b = (k[c][0] > b) ? k[c][0] : b;
#pragma unroll
    for (int off = 32; off > 0; off >>= 1) {
      u64 o = __shfl_xor(b, off);
      b = (o > b) ? o : b;
    }
    if (lane == 0) selLds[wv][it] = (int)(0xFFFFFFFFu - (unsigned)(b & 0xFFFFFFFFu));
#pragma unroll
    for (int c = 0; c < 8; ++c) {
      bool hit = (k[c][0] == b);
      k[c][0] = hit ? k[c][1] : k[c][0];
      k[c][1] = hit ? k[c][2] : k[c][1];
      k[c][2] = hit ? k[c][3] : k[c][2];
      k[c][3] = hit ? 0ull    : k[c][3];
    }
  }

  const float* zrow = z + (size_t)row * DIM;
  const int d0 = lane * 8;
  const float4 za = *(const float4*)(zrow + d0);
  const float4 zb = *(const float4*)(zrow + d0 + 4);
  const float myz2 = g_z2[row];

  double p[NCAND];
  int cidx[NCAND];
#pragma unroll
  for (int c = 0; c < NCAND; ++c) {
    cidx[c] = selLds[wv][c];
    const float* cp = centers + (size_t)cidx[c] * DIM + d0;
    float4 ca = *(const float4*)(cp);
    float4 cb = *(const float4*)(cp + 4);
    p[c] = (double)za.x * ca.x + (double)za.y * ca.y +
           (double)za.z * ca.z + (double)za.w * ca.w +
           (double)zb.x * cb.x + (double)zb.y * cb.y +
           (double)zb.z * cb.z + (double)zb.w * cb.w;
  }
#pragma unroll
  for (int off = 32; off > 0; off >>= 1) {
#pragma unroll
    for (int c = 0; c < NCAND; ++c) p[c] += __shfl_xor(p[c], off);
  }

  float exv[NCAND];
#pragma unroll
  for (int c = 0; c < NCAND; ++c) {
    const int ci = cidx[c];
    float dotf = (float)p[c];
    float t   = __fadd_rn(myz2, g_c2[ci]);
    float sq  = __fsub_rn(t, __fmul_rn(2.0f, dotf));
    float d   = sqrtf(fmaxf(sq, 0.0f));
    float den = __fadd_rn(__fmul_rn(d, d), 1e-6f);
    exv[c] = __fdiv_rn(mus[ci], den);
  }

  unsigned used = 0;
  float tv[KEXP]; int tix[KEXP];
#pragma unroll
  for (int s = 0; s < KEXP; ++s) {
    float bv = -INFINITY; int bi = 0x7FFFFFFF; int bc = 0;
#pragma unroll
    for (int c = 0; c < NCAND; ++c) {
      bool ok = (used & (1u << c)) == 0;
      if (ok && (exv[c] > bv || (exv[c] == bv && cidx[c] < bi))) {
        bv = exv[c]; bi = cidx[c]; bc = c;
      }
    }
    used |= (1u << bc);
    tv[s] = bv; tix[s] = bi;
  }

  float mm = tv[0];
  float w[KEXP];
  float s = 0.0f;
#pragma unroll
  for (int kk = 0; kk < KEXP; ++kk) { w[kk] = expf(tv[kk] - mm); s += w[kk]; }
#pragma unroll
  for (int kk = 0; kk < KEXP; ++kk) w[kk] /= s;

  float comb[8] = {0, 0, 0, 0, 0, 0, 0, 0};
#pragma unroll
  for (int kk = 0; kk < KEXP; ++kk) {
    const float* cp = centers + (size_t)tix[kk] * DIM + d0;
    float4 a = *(const float4*)(cp);
    float4 bq = *(const float4*)(cp + 4);
    comb[0] += w[kk] * a.x;  comb[1] += w[kk] * a.y;
    comb[2] += w[kk] * a.z;  comb[3] += w[kk] * a.w;
    comb[4] += w[kk] * bq.x; comb[5] += w[kk] * bq.y;
    comb[6] += w[kk] * bq.z; comb[7] += w[kk] * bq.w;
  }
  const float zv[8] = {za.x, za.y, za.z, za.w, zb.x, zb.y, zb.z, zb.w};
  float o[8];
#pragma unroll
  for (int e = 0; e < 8; ++e)
    o[e] = __fadd_rn(__fmul_rn(0.7f, zv[e]), __fmul_rn(0.3f, comb[e]));
  *(float4*)(out + (size_t)row * DIM + d0)     = *(float4*)&o[0];
  *(float4*)(out + (size_t)row * DIM + d0 + 4) = *(float4*)&o[4];
}

// ---------------------------------------------------------------------------
extern "C" void kernel_launch(void* const* d_in, const int* in_sizes, int n_in,
                              void* d_out, int out_size, void* d_ws, size_t ws_size,
                              hipStream_t stream) {
  const float* z       = (const float*)d_in[0];
  const float* centers = (const float*)d_in[1];
  const float* mus     = (const float*)d_in[2];
  float* out      = (float*)d_out;
  float* expanded = out;
  float* att      = out + (size_t)BATCH * DIM;

  convert_kernel<<<(BATCH + NC) * DIM / (256 * 8), 256, 0, stream>>>(z, centers);
  attr_bf16<<<(BATCH / BMT) * (NC / BNT), 512, 0, stream>>>(mus, att);
  topk_kernel<<<BATCH / 4, 256, 0, stream>>>(att, z, centers, mus, expanded);
}

// Round 14
// 153.982 us; speedup vs baseline: 1.2983x; 1.2983x over previous
//
#include <hip/hip_runtime.h>
#include <math.h>

#define BATCH 4096
#define NC    8192
#define DIM   512
#define KEXP  5
#define NCAND 10

using bf16x8 = __attribute__((ext_vector_type(8))) short;
using f32x4  = __attribute__((ext_vector_type(4))) float;
typedef unsigned long long u64;

__device__ unsigned short g_zbf[BATCH * DIM];   // 4 MB bf16(z)
__device__ unsigned short g_cbf[NC * DIM];      // 8 MB bf16(centers)
__device__ float g_z2[BATCH];
__device__ float g_c2[NC];
// per (row, 64-col half): top-5 u64 keys + 1 zero pad (sorted desc). 25 MB.
__device__ u64 g_cand[(size_t)BATCH * 128 * 6];

__device__ __forceinline__ u64 umax(u64 a, u64 b) { return a > b ? a : b; }
__device__ __forceinline__ u64 umin(u64 a, u64 b) { return a < b ? a : b; }

__device__ __forceinline__ unsigned short rtne_bf16(float f) {
  unsigned u = __float_as_uint(f);
  u += 0x7FFFu + ((u >> 16) & 1u);
  return (unsigned short)(u >> 16);
}

__device__ __forceinline__ void gload16(const void* g, void* l) {
  __builtin_amdgcn_global_load_lds(
      (const __attribute__((address_space(1))) void*)g,
      (__attribute__((address_space(3))) void*)l, 16, 0, 0);
}

// ---------------------------------------------------------------------------
// Kernel 0: f32 -> bf16 (RTN) conversion FUSED with f64 row-norms.
// ---------------------------------------------------------------------------
__global__ __launch_bounds__(256) void convert_kernel(const float* __restrict__ z,
                                                      const float* __restrict__ c) {
  const size_t i = ((size_t)blockIdx.x * 256 + threadIdx.x) * 8;
  const size_t zn = (size_t)BATCH * DIM;
  const float* src;
  unsigned short* dst;
  float* ndst;
  size_t off;
  if (i < zn) { src = z; dst = g_zbf; ndst = g_z2; off = i; }
  else        { src = c; dst = g_cbf; ndst = g_c2; off = i - zn; }
  float4 a = *(const float4*)(src + off);
  float4 b = *(const float4*)(src + off + 4);
  uint4 o;
  o.x = (unsigned)rtne_bf16(a.x) | ((unsigned)rtne_bf16(a.y) << 16);
  o.y = (unsigned)rtne_bf16(a.z) | ((unsigned)rtne_bf16(a.w) << 16);
  o.z = (unsigned)rtne_bf16(b.x) | ((unsigned)rtne_bf16(b.y) << 16);
  o.w = (unsigned)rtne_bf16(b.z) | ((unsigned)rtne_bf16(b.w) << 16);
  *(uint4*)(dst + off) = o;

  double s = (double)a.x * a.x + (double)a.y * a.y + (double)a.z * a.z + (double)a.w * a.w +
             (double)b.x * b.x + (double)b.y * b.y + (double)b.z * b.z + (double)b.w * b.w;
#pragma unroll
  for (int sh = 32; sh > 0; sh >>= 1) s += __shfl_xor(s, sh);
  if ((threadIdx.x & 63) == 0) ndst[off / DIM] = (float)s;
}

// ---------------------------------------------------------------------------
// Kernel 2: attractions GEMM — gemm_dots' exact loop (measured 6.2 TB/s) +
// dwordx4 att epilogue + fused per-(row, 64-col-half) top-5 key extraction.
// Key = (f32bits<<32)|(~col): u64 order == (value desc, col asc) == jax.
// Per thread: 4-deep insert over its 16 row-values; merge across the 4
// q-lanes (shfl_xor 16 then 32) via sorted-merge identity; q==0 writes
// 5 keys (+pad) to g_cand. Phase-2 then never re-reads att.
// ---------------------------------------------------------------------------
#define BM  128
#define BN  128
#define BKK 64

__global__ __launch_bounds__(256) void attr_bf16(const float* __restrict__ mus,
                                                 float* __restrict__ att) {
  __shared__ __align__(16) unsigned short Ah[BM * BKK];
  __shared__ __align__(16) unsigned short Bh[BM * BKK];

  const int tid  = threadIdx.x;
  const int lane = tid & 63;
  const int wid  = tid >> 6;
  const int wm   = wid >> 1;
  const int wn   = wid & 1;
  const int l15  = lane & 15;
  const int q    = lane >> 4;

  const int flat = blockIdx.x;
  const int swz  = (flat & 7) * 256 + (flat >> 3);
  const int tile_c = swz & 63;
  const int tile_r = swz >> 6;
  const int col0 = tile_c * BN;
  const int row0 = tile_r * BM;

  f32x4 acc[4][4] = {};   // acc[j][i]

  const unsigned short* Ag = g_zbf + (size_t)row0 * DIM;
  const unsigned short* Bg = g_cbf + (size_t)col0 * DIM;

  const int crow = lane >> 3;
  const int gsw  = (lane & 7) ^ crow;

  for (int k0 = 0; k0 < DIM; k0 += BKK) {
#pragma unroll
    for (int j = 0; j < 4; ++j) {
      const int base_row = (wid * 4 + j) * 8;
      const int r = base_row + crow;
      gload16(Ag + (size_t)r * DIM + k0 + gsw * 8, Ah + base_row * 64);
      gload16(Bg + (size_t)r * DIM + k0 + gsw * 8, Bh + base_row * 64);
    }
    __syncthreads();

#pragma unroll
    for (int kk = 0; kk < 2; ++kk) {
      bf16x8 fa[4], fb[4];
#pragma unroll
      for (int i = 0; i < 4; ++i) {
        const int r = wm * 64 + i * 16 + l15;
        const int g = (kk * 4 + q) ^ (r & 7);
        fa[i] = *(const bf16x8*)((const char*)Ah + r * 128 + g * 16);
      }
#pragma unroll
      for (int j2 = 0; j2 < 4; ++j2) {
        const int r = wn * 64 + j2 * 16 + l15;
        const int g = (kk * 4 + q) ^ (r & 7);
        fb[j2] = *(const bf16x8*)((const char*)Bh + r * 128 + g * 16);
      }
#pragma unroll
      for (int j2 = 0; j2 < 4; ++j2)
#pragma unroll
        for (int i = 0; i < 4; ++i)
          acc[j2][i] = __builtin_amdgcn_mfma_f32_16x16x32_bf16(fb[j2], fa[i], acc[j2][i], 0, 0, 0);
    }
    __syncthreads();
  }

  // ---- epilogue: att values (dwordx4 stores) + fused top-5 extraction ----
  const int half = tile_c * 2 + wn;   // global 64-col half index (0..127)
#pragma unroll
  for (int i = 0; i < 4; ++i) {
    const int ar = row0 + wm * 64 + i * 16 + l15;
    const float zz = g_z2[ar];
    float* dst = att + (size_t)ar * NC;

    u64 L0 = 0, L1 = 0, L2 = 0, L3 = 0;   // per-lane 4-deep key list (desc)
#pragma unroll
    for (int j = 0; j < 4; ++j) {
      const int gc0 = col0 + wn * 64 + j * 16 + q * 4;
      const float4 cc = *(const float4*)&g_c2[gc0];
      const float4 mu = *(const float4*)&mus[gc0];
      const float ccv[4] = {cc.x, cc.y, cc.z, cc.w};
      const float muv[4] = {mu.x, mu.y, mu.z, mu.w};
      float o[4];
#pragma unroll
      for (int r = 0; r < 4; ++r) {
        float tt  = __fadd_rn(zz, ccv[r]);
        float sq  = __fsub_rn(tt, __fmul_rn(2.0f, acc[j][i][r]));
        float d   = sqrtf(fmaxf(sq, 0.0f));
        float den = __fadd_rn(__fmul_rn(d, d), 1e-6f);
        o[r] = __fdiv_rn(muv[r], den);
      }
      *(float4*)(dst + gc0) = *(const float4*)o;
#pragma unroll
      for (int r = 0; r < 4; ++r) {
        u64 nk = ((u64)__float_as_uint(o[r]) << 32) | (u64)(0xFFFFFFFFu - (unsigned)(gc0 + r));
        bool b0 = nk > L0, b1 = nk > L1, b2 = nk > L2, b3 = nk > L3;
        u64 t0 = L0, t1 = L1, t2 = L2;
        L0 = b0 ? nk : L0;
        L1 = b0 ? t0 : (b1 ? nk : L1);
        L2 = b1 ? t1 : (b2 ? nk : L2);
        L3 = b2 ? t2 : (b3 ? nk : L3);
      }
    }

    // merge step 1 (xor 16): keep top-4 of 8
    {
      u64 B0 = __shfl_xor(L0, 16), B1 = __shfl_xor(L1, 16);
      u64 B2 = __shfl_xor(L2, 16), B3 = __shfl_xor(L3, 16);
      u64 n0 = umax(L0, B0);
      u64 n1 = umax(umax(L1, B1), umin(L0, B0));
      u64 n2 = umax(umax(L2, B2), umax(umin(L0, B1), umin(L1, B0)));
      u64 n3 = umax(umax(L3, B3), umax(umin(L0, B2), umax(umin(L1, B1), umin(L2, B0))));
      L0 = n0; L1 = n1; L2 = n2; L3 = n3;
    }
    // merge step 2 (xor 32): keep top-5 of 8
    u64 m0, m1, m2, m3, m4;
    {
      u64 C0 = __shfl_xor(L0, 32), C1 = __shfl_xor(L1, 32);
      u64 C2 = __shfl_xor(L2, 32), C3 = __shfl_xor(L3, 32);
      m0 = umax(L0, C0);
      m1 = umax(umax(L1, C1), umin(L0, C0));
      m2 = umax(umax(L2, C2), umax(umin(L0, C1), umin(L1, C0)));
      m3 = umax(umax(L3, C3), umax(umin(L0, C2), umax(umin(L1, C1), umin(L2, C0))));
      m4 = umax(umax(umin(L0, C3), umin(L1, C2)), umax(umin(L2, C1), umin(L3, C0)));
    }
    if (q == 0) {
      u64* cp = &g_cand[((size_t)ar * 128 + half) * 6];
      ulonglong2 w0; w0.x = m0; w0.y = m1;
      ulonglong2 w1; w1.x = m2; w1.y = m3;
      ulonglong2 w2; w2.x = m4; w2.y = 0ull;
      *(ulonglong2*)(cp)     = w0;
      *(ulonglong2*)(cp + 2) = w1;
      *(ulonglong2*)(cp + 4) = w2;
    }
  }
}

// ---------------------------------------------------------------------------
// Kernel 3: phase-2 top-k from g_cand (25 MB instead of re-reading 131 MB).
// Wave per row: lane merges its 2 halves (6+6 -> top-10), 6-step butterfly
// keep-10, then the validated exact-f64 re-rank + softmax + combine tail.
// ---------------------------------------------------------------------------
__global__ __launch_bounds__(256) void topk2(const float* __restrict__ z,
                                             const float* __restrict__ centers,
                                             const float* __restrict__ mus,
                                             float* __restrict__ out) {
  const int lane = threadIdx.x & 63;
  const int row  = blockIdx.x * 4 + (threadIdx.x >> 6);

  // load 2 halves x 6 keys (sorted desc, zero-padded)
  const u64* cp = &g_cand[((size_t)row * 128 + lane * 2) * 6];
  u64 a[6], b[6];
  {
    ulonglong2 p0 = *(const ulonglong2*)(cp);
    ulonglong2 p1 = *(const ulonglong2*)(cp + 2);
    ulonglong2 p2 = *(const ulonglong2*)(cp + 4);
    a[0] = p0.x; a[1] = p0.y; a[2] = p1.x; a[3] = p1.y; a[4] = p2.x; a[5] = p2.y;
    ulonglong2 p3 = *(const ulonglong2*)(cp + 6);
    ulonglong2 p4 = *(const ulonglong2*)(cp + 8);
    ulonglong2 p5 = *(const ulonglong2*)(cp + 10);
    b[0] = p3.x; b[1] = p3.y; b[2] = p4.x; b[3] = p4.y; b[4] = p5.x; b[5] = p5.y;
  }

  // lane-local: top-10 of the two sorted-6 lists
  u64 s[10];
#pragma unroll
  for (int k = 0; k < 10; ++k) {
    u64 best = 0;
    if (k < 6) best = umax(a[k], b[k]);
#pragma unroll
    for (int i2 = 0; i2 < 6; ++i2) {
      const int j2 = k - 1 - i2;
      if (j2 >= 0 && j2 < 6) best = umax(best, umin(a[i2], b[j2]));
    }
    s[k] = best;
  }

  // butterfly: merge sorted-10 lists across lanes, keep top-10
#pragma unroll
  for (int msk = 1; msk < 64; msk <<= 1) {
    u64 t[10];
#pragma unroll
    for (int k = 0; k < 10; ++k) t[k] = __shfl_xor(s[k], msk);
    u64 r2[10];
#pragma unroll
    for (int k = 0; k < 10; ++k) {
      u64 best = umax(s[k], t[k]);
#pragma unroll
      for (int i2 = 0; i2 < 10; ++i2) {
        const int j2 = k - 1 - i2;
        if (j2 >= 0 && j2 < 10) best = umax(best, umin(s[i2], t[j2]));
      }
      r2[k] = best;
    }
#pragma unroll
    for (int k = 0; k < 10; ++k) s[k] = r2[k];
  }

  int cidx[NCAND];
#pragma unroll
  for (int c = 0; c < NCAND; ++c)
    cidx[c] = (int)(0xFFFFFFFFu - (unsigned)(s[c] & 0xFFFFFFFFull));

  // ---- exact f64 re-computation of the NCAND candidates (validated) ----
  const float* zrow = z + (size_t)row * DIM;
  const int d0 = lane * 8;
  const float4 za = *(const float4*)(zrow + d0);
  const float4 zb = *(const float4*)(zrow + d0 + 4);
  const float myz2 = g_z2[row];

  double p[NCAND];
#pragma unroll
  for (int c = 0; c < NCAND; ++c) {
    const float* cptr = centers + (size_t)cidx[c] * DIM + d0;
    float4 ca = *(const float4*)(cptr);
    float4 cb = *(const float4*)(cptr + 4);
    p[c] = (double)za.x * ca.x + (double)za.y * ca.y +
           (double)za.z * ca.z + (double)za.w * ca.w +
           (double)zb.x * cb.x + (double)zb.y * cb.y +
           (double)zb.z * cb.z + (double)zb.w * cb.w;
  }
#pragma unroll
  for (int off = 32; off > 0; off >>= 1) {
#pragma unroll
    for (int c = 0; c < NCAND; ++c) p[c] += __shfl_xor(p[c], off);
  }

  float exv[NCAND];
#pragma unroll
  for (int c = 0; c < NCAND; ++c) {
    const int ci = cidx[c];
    float dotf = (float)p[c];
    float t   = __fadd_rn(myz2, g_c2[ci]);
    float sq  = __fsub_rn(t, __fmul_rn(2.0f, dotf));
    float d   = sqrtf(fmaxf(sq, 0.0f));
    float den = __fadd_rn(__fmul_rn(d, d), 1e-6f);
    exv[c] = __fdiv_rn(mus[ci], den);
  }

  unsigned used = 0;
  float tv[KEXP]; int tix[KEXP];
#pragma unroll
  for (int s2 = 0; s2 < KEXP; ++s2) {
    float bv = -INFINITY; int bi = 0x7FFFFFFF; int bc = 0;
#pragma unroll
    for (int c = 0; c < NCAND; ++c) {
      bool ok = (used & (1u << c)) == 0;
      if (ok && (exv[c] > bv || (exv[c] == bv && cidx[c] < bi))) {
        bv = exv[c]; bi = cidx[c]; bc = c;
      }
    }
    used |= (1u << bc);
    tv[s2] = bv; tix[s2] = bi;
  }

  float mm = tv[0];
  float w[KEXP];
  float ssum = 0.0f;
#pragma unroll
  for (int kk = 0; kk < KEXP; ++kk) { w[kk] = expf(tv[kk] - mm); ssum += w[kk]; }
#pragma unroll
  for (int kk = 0; kk < KEXP; ++kk) w[kk] /= ssum;

  float comb[8] = {0, 0, 0, 0, 0, 0, 0, 0};
#pragma unroll
  for (int kk = 0; kk < KEXP; ++kk) {
    const float* cptr = centers + (size_t)tix[kk] * DIM + d0;
    float4 aq = *(const float4*)(cptr);
    float4 bq = *(const float4*)(cptr + 4);
    comb[0] += w[kk] * aq.x; comb[1] += w[kk] * aq.y;
    comb[2] += w[kk] * aq.z; comb[3] += w[kk] * aq.w;
    comb[4] += w[kk] * bq.x; comb[5] += w[kk] * bq.y;
    comb[6] += w[kk] * bq.z; comb[7] += w[kk] * bq.w;
  }
  const float zv[8] = {za.x, za.y, za.z, za.w, zb.x, zb.y, zb.z, zb.w};
  float o[8];
#pragma unroll
  for (int e = 0; e < 8; ++e)
    o[e] = __fadd_rn(__fmul_rn(0.7f, zv[e]), __fmul_rn(0.3f, comb[e]));
  *(float4*)(out + (size_t)row * DIM + d0)     = *(float4*)&o[0];
  *(float4*)(out + (size_t)row * DIM + d0 + 4) = *(float4*)&o[4];
}

// ---------------------------------------------------------------------------
extern "C" void kernel_launch(void* const* d_in, const int* in_sizes, int n_in,
                              void* d_out, int out_size, void* d_ws, size_t ws_size,
                              hipStream_t stream) {
  const float* z       = (const float*)d_in[0];
  const float* centers = (const float*)d_in[1];
  const float* mus     = (const float*)d_in[2];
  float* out      = (float*)d_out;
  float* expanded = out;
  float* att      = out + (size_t)BATCH * DIM;

  convert_kernel<<<(BATCH + NC) * DIM / (256 * 8), 256, 0, stream>>>(z, centers);
  attr_bf16<<<(BATCH / BM) * (NC / BN), 256, 0, stream>>>(mus, att);
  topk2<<<BATCH / 4, 256, 0, stream>>>(z, centers, mus, expanded);
}

// Round 15
// 146.411 us; speedup vs baseline: 1.3654x; 1.0517x over previous
//
#include <hip/hip_runtime.h>
#include <math.h>

#define BATCH 4096
#define NC    8192
#define DIM   512
#define KEXP  5
#define NCAND 10

using bf16x8 = __attribute__((ext_vector_type(8))) short;
using f32x4  = __attribute__((ext_vector_type(4))) float;
typedef unsigned long long u64;

__device__ unsigned short g_zbf[BATCH * DIM];   // 4 MB bf16(z)
__device__ unsigned short g_cbf[NC * DIM];      // 8 MB bf16(centers)
__device__ float g_z2[BATCH];
__device__ float g_c2[NC];
// per (row, 64-col half): top-5 u64 keys + 1 zero pad (sorted desc). 25 MB.
__device__ u64 g_cand[(size_t)BATCH * 128 * 6];

__device__ __forceinline__ u64 umax(u64 a, u64 b) { return a > b ? a : b; }
__device__ __forceinline__ u64 umin(u64 a, u64 b) { return a < b ? a : b; }

__device__ __forceinline__ unsigned short rtne_bf16(float f) {
  unsigned u = __float_as_uint(f);
  u += 0x7FFFu + ((u >> 16) & 1u);
  return (unsigned short)(u >> 16);
}

__device__ __forceinline__ void gload16(const void* g, void* l) {
  __builtin_amdgcn_global_load_lds(
      (const __attribute__((address_space(1))) void*)g,
      (__attribute__((address_space(3))) void*)l, 16, 0, 0);
}

// ---------------------------------------------------------------------------
// Kernel 0: f32 -> bf16 (RTN) conversion FUSED with f64 row-norms.
// ---------------------------------------------------------------------------
__global__ __launch_bounds__(256) void convert_kernel(const float* __restrict__ z,
                                                      const float* __restrict__ c) {
  const size_t i = ((size_t)blockIdx.x * 256 + threadIdx.x) * 8;
  const size_t zn = (size_t)BATCH * DIM;
  const float* src;
  unsigned short* dst;
  float* ndst;
  size_t off;
  if (i < zn) { src = z; dst = g_zbf; ndst = g_z2; off = i; }
  else        { src = c; dst = g_cbf; ndst = g_c2; off = i - zn; }
  float4 a = *(const float4*)(src + off);
  float4 b = *(const float4*)(src + off + 4);
  uint4 o;
  o.x = (unsigned)rtne_bf16(a.x) | ((unsigned)rtne_bf16(a.y) << 16);
  o.y = (unsigned)rtne_bf16(a.z) | ((unsigned)rtne_bf16(a.w) << 16);
  o.z = (unsigned)rtne_bf16(b.x) | ((unsigned)rtne_bf16(b.y) << 16);
  o.w = (unsigned)rtne_bf16(b.z) | ((unsigned)rtne_bf16(b.w) << 16);
  *(uint4*)(dst + off) = o;

  double s = (double)a.x * a.x + (double)a.y * a.y + (double)a.z * a.z + (double)a.w * a.w +
             (double)b.x * b.x + (double)b.y * b.y + (double)b.z * b.z + (double)b.w * b.w;
#pragma unroll
  for (int sh = 32; sh > 0; sh >>= 1) s += __shfl_xor(s, sh);
  if ((threadIdx.x & 63) == 0) ndst[off / DIM] = (float)s;
}

// ---------------------------------------------------------------------------
// Kernel 2: attractions GEMM + dwordx4 att epilogue + fused per-(row,
// 64-col-half) top-5 key extraction (validated round 14). ONE change vs r14:
// block->tile mapping is the COLUMN-MAJOR XCD STRIP walk (r7, measured
// FETCH 41 MB): each XCD owns 4 tile-rows (A strip L2-resident) and walks
// its 64 tile-cols down-column, so each B col-panel is fetched once per XCD.
// ---------------------------------------------------------------------------
#define BM  128
#define BN  128
#define BKK 64

__global__ __launch_bounds__(256) void attr_bf16(const float* __restrict__ mus,
                                                 float* __restrict__ att) {
  __shared__ __align__(16) unsigned short Ah[BM * BKK];
  __shared__ __align__(16) unsigned short Bh[BM * BKK];

  const int tid  = threadIdx.x;
  const int lane = tid & 63;
  const int wid  = tid >> 6;
  const int wm   = wid >> 1;
  const int wn   = wid & 1;
  const int l15  = lane & 15;
  const int q    = lane >> 4;

  // column-major XCD strip walk (r7-validated): xcd owns 4 tile-rows
  const int flat = blockIdx.x;          // 2048 blocks
  const int xcd  = flat & 7;
  const int t    = flat >> 3;           // 0..255
  const int row0 = (xcd * 4 + (t & 3)) * BM;
  const int tile_c = t >> 2;            // 0..63
  const int col0 = tile_c * BN;

  f32x4 acc[4][4] = {};   // acc[j][i]

  const unsigned short* Ag = g_zbf + (size_t)row0 * DIM;
  const unsigned short* Bg = g_cbf + (size_t)col0 * DIM;

  const int crow = lane >> 3;
  const int gsw  = (lane & 7) ^ crow;

  for (int k0 = 0; k0 < DIM; k0 += BKK) {
#pragma unroll
    for (int j = 0; j < 4; ++j) {
      const int base_row = (wid * 4 + j) * 8;
      const int r = base_row + crow;
      gload16(Ag + (size_t)r * DIM + k0 + gsw * 8, Ah + base_row * 64);
      gload16(Bg + (size_t)r * DIM + k0 + gsw * 8, Bh + base_row * 64);
    }
    __syncthreads();

#pragma unroll
    for (int kk = 0; kk < 2; ++kk) {
      bf16x8 fa[4], fb[4];
#pragma unroll
      for (int i = 0; i < 4; ++i) {
        const int r = wm * 64 + i * 16 + l15;
        const int g = (kk * 4 + q) ^ (r & 7);
        fa[i] = *(const bf16x8*)((const char*)Ah + r * 128 + g * 16);
      }
#pragma unroll
      for (int j2 = 0; j2 < 4; ++j2) {
        const int r = wn * 64 + j2 * 16 + l15;
        const int g = (kk * 4 + q) ^ (r & 7);
        fb[j2] = *(const bf16x8*)((const char*)Bh + r * 128 + g * 16);
      }
#pragma unroll
      for (int j2 = 0; j2 < 4; ++j2)
#pragma unroll
        for (int i = 0; i < 4; ++i)
          acc[j2][i] = __builtin_amdgcn_mfma_f32_16x16x32_bf16(fb[j2], fa[i], acc[j2][i], 0, 0, 0);
    }
    __syncthreads();
  }

  // ---- epilogue: att values (dwordx4 stores) + fused top-5 extraction ----
  const int half = tile_c * 2 + wn;   // global 64-col half index (0..127)
#pragma unroll
  for (int i = 0; i < 4; ++i) {
    const int ar = row0 + wm * 64 + i * 16 + l15;
    const float zz = g_z2[ar];
    float* dst = att + (size_t)ar * NC;

    u64 L0 = 0, L1 = 0, L2 = 0, L3 = 0;   // per-lane 4-deep key list (desc)
#pragma unroll
    for (int j = 0; j < 4; ++j) {
      const int gc0 = col0 + wn * 64 + j * 16 + q * 4;
      const float4 cc = *(const float4*)&g_c2[gc0];
      const float4 mu = *(const float4*)&mus[gc0];
      const float ccv[4] = {cc.x, cc.y, cc.z, cc.w};
      const float muv[4] = {mu.x, mu.y, mu.z, mu.w};
      float o[4];
#pragma unroll
      for (int r = 0; r < 4; ++r) {
        float tt  = __fadd_rn(zz, ccv[r]);
        float sq  = __fsub_rn(tt, __fmul_rn(2.0f, acc[j][i][r]));
        float d   = sqrtf(fmaxf(sq, 0.0f));
        float den = __fadd_rn(__fmul_rn(d, d), 1e-6f);
        o[r] = __fdiv_rn(muv[r], den);
      }
      *(float4*)(dst + gc0) = *(const float4*)o;
#pragma unroll
      for (int r = 0; r < 4; ++r) {
        u64 nk = ((u64)__float_as_uint(o[r]) << 32) | (u64)(0xFFFFFFFFu - (unsigned)(gc0 + r));
        bool b0 = nk > L0, b1 = nk > L1, b2 = nk > L2, b3 = nk > L3;
        u64 t0 = L0, t1 = L1, t2 = L2;
        L0 = b0 ? nk : L0;
        L1 = b0 ? t0 : (b1 ? nk : L1);
        L2 = b1 ? t1 : (b2 ? nk : L2);
        L3 = b2 ? t2 : (b3 ? nk : L3);
      }
    }

    // merge step 1 (xor 16): keep top-4 of 8
    {
      u64 B0 = __shfl_xor(L0, 16), B1 = __shfl_xor(L1, 16);
      u64 B2 = __shfl_xor(L2, 16), B3 = __shfl_xor(L3, 16);
      u64 n0 = umax(L0, B0);
      u64 n1 = umax(umax(L1, B1), umin(L0, B0));
      u64 n2 = umax(umax(L2, B2), umax(umin(L0, B1), umin(L1, B0)));
      u64 n3 = umax(umax(L3, B3), umax(umin(L0, B2), umax(umin(L1, B1), umin(L2, B0))));
      L0 = n0; L1 = n1; L2 = n2; L3 = n3;
    }
    // merge step 2 (xor 32): keep top-5 of 8
    u64 m0, m1, m2, m3, m4;
    {
      u64 C0 = __shfl_xor(L0, 32), C1 = __shfl_xor(L1, 32);
      u64 C2 = __shfl_xor(L2, 32), C3 = __shfl_xor(L3, 32);
      m0 = umax(L0, C0);
      m1 = umax(umax(L1, C1), umin(L0, C0));
      m2 = umax(umax(L2, C2), umax(umin(L0, C1), umin(L1, C0)));
      m3 = umax(umax(L3, C3), umax(umin(L0, C2), umax(umin(L1, C1), umin(L2, C0))));
      m4 = umax(umax(umin(L0, C3), umin(L1, C2)), umax(umin(L2, C1), umin(L3, C0)));
    }
    if (q == 0) {
      u64* cp = &g_cand[((size_t)ar * 128 + half) * 6];
      ulonglong2 w0; w0.x = m0; w0.y = m1;
      ulonglong2 w1; w1.x = m2; w1.y = m3;
      ulonglong2 w2; w2.x = m4; w2.y = 0ull;
      *(ulonglong2*)(cp)     = w0;
      *(ulonglong2*)(cp + 2) = w1;
      *(ulonglong2*)(cp + 4) = w2;
    }
  }
}

// ---------------------------------------------------------------------------
// Kernel 3: phase-2 top-k from g_cand (25 MB; att never re-read).
// ---------------------------------------------------------------------------
__global__ __launch_bounds__(256) void topk2(const float* __restrict__ z,
                                             const float* __restrict__ centers,
                                             const float* __restrict__ mus,
                                             float* __restrict__ out) {
  const int lane = threadIdx.x & 63;
  const int row  = blockIdx.x * 4 + (threadIdx.x >> 6);

  const u64* cp = &g_cand[((size_t)row * 128 + lane * 2) * 6];
  u64 a[6], b[6];
  {
    ulonglong2 p0 = *(const ulonglong2*)(cp);
    ulonglong2 p1 = *(const ulonglong2*)(cp + 2);
    ulonglong2 p2 = *(const ulonglong2*)(cp + 4);
    a[0] = p0.x; a[1] = p0.y; a[2] = p1.x; a[3] = p1.y; a[4] = p2.x; a[5] = p2.y;
    ulonglong2 p3 = *(const ulonglong2*)(cp + 6);
    ulonglong2 p4 = *(const ulonglong2*)(cp + 8);
    ulonglong2 p5 = *(const ulonglong2*)(cp + 10);
    b[0] = p3.x; b[1] = p3.y; b[2] = p4.x; b[3] = p4.y; b[4] = p5.x; b[5] = p5.y;
  }

  u64 s[10];
#pragma unroll
  for (int k = 0; k < 10; ++k) {
    u64 best = 0;
    if (k < 6) best = umax(a[k], b[k]);
#pragma unroll
    for (int i2 = 0; i2 < 6; ++i2) {
      const int j2 = k - 1 - i2;
      if (j2 >= 0 && j2 < 6) best = umax(best, umin(a[i2], b[j2]));
    }
    s[k] = best;
  }

#pragma unroll
  for (int msk = 1; msk < 64; msk <<= 1) {
    u64 t[10];
#pragma unroll
    for (int k = 0; k < 10; ++k) t[k] = __shfl_xor(s[k], msk);
    u64 r2[10];
#pragma unroll
    for (int k = 0; k < 10; ++k) {
      u64 best = umax(s[k], t[k]);
#pragma unroll
      for (int i2 = 0; i2 < 10; ++i2) {
        const int j2 = k - 1 - i2;
        if (j2 >= 0 && j2 < 10) best = umax(best, umin(s[i2], t[j2]));
      }
      r2[k] = best;
    }
#pragma unroll
    for (int k = 0; k < 10; ++k) s[k] = r2[k];
  }

  int cidx[NCAND];
#pragma unroll
  for (int c = 0; c < NCAND; ++c)
    cidx[c] = (int)(0xFFFFFFFFu - (unsigned)(s[c] & 0xFFFFFFFFull));

  const float* zrow = z + (size_t)row * DIM;
  const int d0 = lane * 8;
  const float4 za = *(const float4*)(zrow + d0);
  const float4 zb = *(const float4*)(zrow + d0 + 4);
  const float myz2 = g_z2[row];

  double p[NCAND];
#pragma unroll
  for (int c = 0; c < NCAND; ++c) {
    const float* cptr = centers + (size_t)cidx[c] * DIM + d0;
    float4 ca = *(const float4*)(cptr);
    float4 cb = *(const float4*)(cptr + 4);
    p[c] = (double)za.x * ca.x + (double)za.y * ca.y +
           (double)za.z * ca.z + (double)za.w * ca.w +
           (double)zb.x * cb.x + (double)zb.y * cb.y +
           (double)zb.z * cb.z + (double)zb.w * cb.w;
  }
#pragma unroll
  for (int off = 32; off > 0; off >>= 1) {
#pragma unroll
    for (int c = 0; c < NCAND; ++c) p[c] += __shfl_xor(p[c], off);
  }

  float exv[NCAND];
#pragma unroll
  for (int c = 0; c < NCAND; ++c) {
    const int ci = cidx[c];
    float dotf = (float)p[c];
    float t   = __fadd_rn(myz2, g_c2[ci]);
    float sq  = __fsub_rn(t, __fmul_rn(2.0f, dotf));
    float d   = sqrtf(fmaxf(sq, 0.0f));
    float den = __fadd_rn(__fmul_rn(d, d), 1e-6f);
    exv[c] = __fdiv_rn(mus[ci], den);
  }

  unsigned used = 0;
  float tv[KEXP]; int tix[KEXP];
#pragma unroll
  for (int s2 = 0; s2 < KEXP; ++s2) {
    float bv = -INFINITY; int bi = 0x7FFFFFFF; int bc = 0;
#pragma unroll
    for (int c = 0; c < NCAND; ++c) {
      bool ok = (used & (1u << c)) == 0;
      if (ok && (exv[c] > bv || (exv[c] == bv && cidx[c] < bi))) {
        bv = exv[c]; bi = cidx[c]; bc = c;
      }
    }
    used |= (1u << bc);
    tv[s2] = bv; tix[s2] = bi;
  }

  float mm = tv[0];
  float w[KEXP];
  float ssum = 0.0f;
#pragma unroll
  for (int kk = 0; kk < KEXP; ++kk) { w[kk] = expf(tv[kk] - mm); ssum += w[kk]; }
#pragma unroll
  for (int kk = 0; kk < KEXP; ++kk) w[kk] /= ssum;

  float comb[8] = {0, 0, 0, 0, 0, 0, 0, 0};
#pragma unroll
  for (int kk = 0; kk < KEXP; ++kk) {
    const float* cptr = centers + (size_t)tix[kk] * DIM + d0;
    float4 aq = *(const float4*)(cptr);
    float4 bq = *(const float4*)(cptr + 4);
    comb[0] += w[kk] * aq.x; comb[1] += w[kk] * aq.y;
    comb[2] += w[kk] * aq.z; comb[3] += w[kk] * aq.w;
    comb[4] += w[kk] * bq.x; comb[5] += w[kk] * bq.y;
    comb[6] += w[kk] * bq.z; comb[7] += w[kk] * bq.w;
  }
  const float zv[8] = {za.x, za.y, za.z, za.w, zb.x, zb.y, zb.z, zb.w};
  float o[8];
#pragma unroll
  for (int e = 0; e < 8; ++e)
    o[e] = __fadd_rn(__fmul_rn(0.7f, zv[e]), __fmul_rn(0.3f, comb[e]));
  *(float4*)(out + (size_t)row * DIM + d0)     = *(float4*)&o[0];
  *(float4*)(out + (size_t)row * DIM + d0 + 4) = *(float4*)&o[4];
}

// ---------------------------------------------------------------------------
extern "C" void kernel_launch(void* const* d_in, const int* in_sizes, int n_in,
                              void* d_out, int out_size, void* d_ws, size_t ws_size,
                              hipStream_t stream) {
  const float* z       = (const float*)d_in[0];
  const float* centers = (const float*)d_in[1];
  const float* mus     = (const float*)d_in[2];
  float* out      = (float*)d_out;
  float* expanded = out;
  float* att      = out + (size_t)BATCH * DIM;

  convert_kernel<<<(BATCH + NC) * DIM / (256 * 8), 256, 0, stream>>>(z, centers);
  attr_bf16<<<(BATCH / BM) * (NC / BN), 256, 0, stream>>>(mus, att);
  topk2<<<BATCH / 4, 256, 0, stream>>>(z, centers, mus, expanded);
}

// Round 16
// 145.410 us; speedup vs baseline: 1.3748x; 1.0069x over previous
//
#include <hip/hip_runtime.h>
#include <math.h>

#define BATCH 4096
#define NC    8192
#define DIM   512
#define KEXP  5
#define NCAND 10

using bf16x8 = __attribute__((ext_vector_type(8))) short;
using f32x4  = __attribute__((ext_vector_type(4))) float;
typedef unsigned long long u64;

__device__ unsigned short g_zbf[BATCH * DIM];   // 4 MB bf16(z)
__device__ unsigned short g_cbf[NC * DIM];      // 8 MB bf16(centers)
__device__ float g_z2[BATCH];
__device__ float g_c2[NC];
// per (row, 64-col half): top-5 u64 keys + 1 zero pad (sorted desc). 25 MB.
__device__ u64 g_cand[(size_t)BATCH * 128 * 6];

__device__ __forceinline__ u64 umax(u64 a, u64 b) { return a > b ? a : b; }
__device__ __forceinline__ u64 umin(u64 a, u64 b) { return a < b ? a : b; }
__device__ __forceinline__ void cswap(u64& x, u64& y) {
  u64 h = umax(x, y), l = umin(x, y); x = h; y = l;
}
// merge two sorted-desc 4-lists, keep top-4 (r14-proven identity)
__device__ __forceinline__ void merge44(u64& L0, u64& L1, u64& L2, u64& L3,
                                        u64 q0, u64 q1, u64 q2, u64 q3) {
  u64 m0 = umax(L0, q0);
  u64 m1 = umax(umax(L1, q1), umin(L0, q0));
  u64 m2 = umax(umax(L2, q2), umax(umin(L0, q1), umin(L1, q0)));
  u64 m3 = umax(umax(L3, q3), umax(umin(L0, q2), umax(umin(L1, q1), umin(L2, q0))));
  L0 = m0; L1 = m1; L2 = m2; L3 = m3;
}

__device__ __forceinline__ unsigned short rtne_bf16(float f) {
  unsigned u = __float_as_uint(f);
  u += 0x7FFFu + ((u >> 16) & 1u);
  return (unsigned short)(u >> 16);
}

__device__ __forceinline__ void gload16(const void* g, void* l) {
  __builtin_amdgcn_global_load_lds(
      (const __attribute__((address_space(1))) void*)g,
      (__attribute__((address_space(3))) void*)l, 16, 0, 0);
}

// ---------------------------------------------------------------------------
// Kernel 0: f32 -> bf16 (RTN) conversion FUSED with f64 row-norms.
// ---------------------------------------------------------------------------
__global__ __launch_bounds__(256) void convert_kernel(const float* __restrict__ z,
                                                      const float* __restrict__ c) {
  const size_t i = ((size_t)blockIdx.x * 256 + threadIdx.x) * 8;
  const size_t zn = (size_t)BATCH * DIM;
  const float* src;
  unsigned short* dst;
  float* ndst;
  size_t off;
  if (i < zn) { src = z; dst = g_zbf; ndst = g_z2; off = i; }
  else        { src = c; dst = g_cbf; ndst = g_c2; off = i - zn; }
  float4 a = *(const float4*)(src + off);
  float4 b = *(const float4*)(src + off + 4);
  uint4 o;
  o.x = (unsigned)rtne_bf16(a.x) | ((unsigned)rtne_bf16(a.y) << 16);
  o.y = (unsigned)rtne_bf16(a.z) | ((unsigned)rtne_bf16(a.w) << 16);
  o.z = (unsigned)rtne_bf16(b.x) | ((unsigned)rtne_bf16(b.y) << 16);
  o.w = (unsigned)rtne_bf16(b.z) | ((unsigned)rtne_bf16(b.w) << 16);
  *(uint4*)(dst + off) = o;

  double s = (double)a.x * a.x + (double)a.y * a.y + (double)a.z * a.z + (double)a.w * a.w +
             (double)b.x * b.x + (double)b.y * b.y + (double)b.z * b.z + (double)b.w * b.w;
#pragma unroll
  for (int sh = 32; sh > 0; sh >>= 1) s += __shfl_xor(s, sh);
  if ((threadIdx.x & 63) == 0) ndst[off / DIM] = (float)s;
}

// ---------------------------------------------------------------------------
// Kernel 2: attractions GEMM + dwordx4 att epilogue + fused top-5 extraction.
// r15 structure (column-major XCD strip, FETCH 41 MB) with ONE change:
// the per-lane 16-value depth-4 INSERTION (288 instr, chain ~80) is replaced
// by 4x sort-4 networks + incremental sorted merge44 (~176 instr, chain ~16).
// Key = (f32bits<<32)|(~col): u64 order == (value desc, col asc) == jax;
// keys unique -> sort/merge semantics identical to insertion.
// ---------------------------------------------------------------------------
#define BM  128
#define BN  128
#define BKK 64

__global__ __launch_bounds__(256) void attr_bf16(const float* __restrict__ mus,
                                                 float* __restrict__ att) {
  __shared__ __align__(16) unsigned short Ah[BM * BKK];
  __shared__ __align__(16) unsigned short Bh[BM * BKK];

  const int tid  = threadIdx.x;
  const int lane = tid & 63;
  const int wid  = tid >> 6;
  const int wm   = wid >> 1;
  const int wn   = wid & 1;
  const int l15  = lane & 15;
  const int q    = lane >> 4;

  // column-major XCD strip walk: xcd owns 4 tile-rows
  const int flat = blockIdx.x;          // 2048 blocks
  const int xcd  = flat & 7;
  const int t    = flat >> 3;           // 0..255
  const int row0 = (xcd * 4 + (t & 3)) * BM;
  const int tile_c = t >> 2;            // 0..63
  const int col0 = tile_c * BN;

  f32x4 acc[4][4] = {};   // acc[j][i]

  const unsigned short* Ag = g_zbf + (size_t)row0 * DIM;
  const unsigned short* Bg = g_cbf + (size_t)col0 * DIM;

  const int crow = lane >> 3;
  const int gsw  = (lane & 7) ^ crow;

  for (int k0 = 0; k0 < DIM; k0 += BKK) {
#pragma unroll
    for (int j = 0; j < 4; ++j) {
      const int base_row = (wid * 4 + j) * 8;
      const int r = base_row + crow;
      gload16(Ag + (size_t)r * DIM + k0 + gsw * 8, Ah + base_row * 64);
      gload16(Bg + (size_t)r * DIM + k0 + gsw * 8, Bh + base_row * 64);
    }
    __syncthreads();

#pragma unroll
    for (int kk = 0; kk < 2; ++kk) {
      bf16x8 fa[4], fb[4];
#pragma unroll
      for (int i = 0; i < 4; ++i) {
        const int r = wm * 64 + i * 16 + l15;
        const int g = (kk * 4 + q) ^ (r & 7);
        fa[i] = *(const bf16x8*)((const char*)Ah + r * 128 + g * 16);
      }
#pragma unroll
      for (int j2 = 0; j2 < 4; ++j2) {
        const int r = wn * 64 + j2 * 16 + l15;
        const int g = (kk * 4 + q) ^ (r & 7);
        fb[j2] = *(const bf16x8*)((const char*)Bh + r * 128 + g * 16);
      }
#pragma unroll
      for (int j2 = 0; j2 < 4; ++j2)
#pragma unroll
        for (int i = 0; i < 4; ++i)
          acc[j2][i] = __builtin_amdgcn_mfma_f32_16x16x32_bf16(fb[j2], fa[i], acc[j2][i], 0, 0, 0);
    }
    __syncthreads();
  }

  // ---- epilogue: att values (dwordx4 stores) + fused top-5 extraction ----
  const int half = tile_c * 2 + wn;   // global 64-col half index (0..127)
#pragma unroll
  for (int i = 0; i < 4; ++i) {
    const int ar = row0 + wm * 64 + i * 16 + l15;
    const float zz = g_z2[ar];
    float* dst = att + (size_t)ar * NC;

    u64 L0 = 0, L1 = 0, L2 = 0, L3 = 0;   // sorted-desc top-4 of seen quads
#pragma unroll
    for (int j = 0; j < 4; ++j) {
      const int gc0 = col0 + wn * 64 + j * 16 + q * 4;
      const float4 cc = *(const float4*)&g_c2[gc0];
      const float4 mu = *(const float4*)&mus[gc0];
      const float ccv[4] = {cc.x, cc.y, cc.z, cc.w};
      const float muv[4] = {mu.x, mu.y, mu.z, mu.w};
      float o[4];
#pragma unroll
      for (int r = 0; r < 4; ++r) {
        float tt  = __fadd_rn(zz, ccv[r]);
        float sq  = __fsub_rn(tt, __fmul_rn(2.0f, acc[j][i][r]));
        float d   = sqrtf(fmaxf(sq, 0.0f));
        float den = __fadd_rn(__fmul_rn(d, d), 1e-6f);
        o[r] = __fdiv_rn(muv[r], den);
      }
      *(float4*)(dst + gc0) = *(const float4*)o;

      // quad keys -> sort-4 network (desc) -> merge into running top-4
      u64 q0 = ((u64)__float_as_uint(o[0]) << 32) | (u64)(0xFFFFFFFFu - (unsigned)(gc0 + 0));
      u64 q1 = ((u64)__float_as_uint(o[1]) << 32) | (u64)(0xFFFFFFFFu - (unsigned)(gc0 + 1));
      u64 q2 = ((u64)__float_as_uint(o[2]) << 32) | (u64)(0xFFFFFFFFu - (unsigned)(gc0 + 2));
      u64 q3 = ((u64)__float_as_uint(o[3]) << 32) | (u64)(0xFFFFFFFFu - (unsigned)(gc0 + 3));
      cswap(q0, q1); cswap(q2, q3); cswap(q0, q2); cswap(q1, q3); cswap(q1, q2);
      if (j == 0) { L0 = q0; L1 = q1; L2 = q2; L3 = q3; }
      else        merge44(L0, L1, L2, L3, q0, q1, q2, q3);
    }

    // merge step 1 (xor 16): keep top-4 of 8
    {
      u64 B0 = __shfl_xor(L0, 16), B1 = __shfl_xor(L1, 16);
      u64 B2 = __shfl_xor(L2, 16), B3 = __shfl_xor(L3, 16);
      merge44(L0, L1, L2, L3, B0, B1, B2, B3);
    }
    // merge step 2 (xor 32): keep top-5 of 8
    u64 m0, m1, m2, m3, m4;
    {
      u64 C0 = __shfl_xor(L0, 32), C1 = __shfl_xor(L1, 32);
      u64 C2 = __shfl_xor(L2, 32), C3 = __shfl_xor(L3, 32);
      m0 = umax(L0, C0);
      m1 = umax(umax(L1, C1), umin(L0, C0));
      m2 = umax(umax(L2, C2), umax(umin(L0, C1), umin(L1, C0)));
      m3 = umax(umax(L3, C3), umax(umin(L0, C2), umax(umin(L1, C1), umin(L2, C0))));
      m4 = umax(umax(umin(L0, C3), umin(L1, C2)), umax(umin(L2, C1), umin(L3, C0)));
    }
    if (q == 0) {
      u64* cp = &g_cand[((size_t)ar * 128 + half) * 6];
      ulonglong2 w0; w0.x = m0; w0.y = m1;
      ulonglong2 w1; w1.x = m2; w1.y = m3;
      ulonglong2 w2; w2.x = m4; w2.y = 0ull;
      *(ulonglong2*)(cp)     = w0;
      *(ulonglong2*)(cp + 2) = w1;
      *(ulonglong2*)(cp + 4) = w2;
    }
  }
}

// ---------------------------------------------------------------------------
// Kernel 3: phase-2 top-k from g_cand (25 MB; att never re-read).
// ---------------------------------------------------------------------------
__global__ __launch_bounds__(256) void topk2(const float* __restrict__ z,
                                             const float* __restrict__ centers,
                                             const float* __restrict__ mus,
                                             float* __restrict__ out) {
  const int lane = threadIdx.x & 63;
  const int row  = blockIdx.x * 4 + (threadIdx.x >> 6);

  const u64* cp = &g_cand[((size_t)row * 128 + lane * 2) * 6];
  u64 a[6], b[6];
  {
    ulonglong2 p0 = *(const ulonglong2*)(cp);
    ulonglong2 p1 = *(const ulonglong2*)(cp + 2);
    ulonglong2 p2 = *(const ulonglong2*)(cp + 4);
    a[0] = p0.x; a[1] = p0.y; a[2] = p1.x; a[3] = p1.y; a[4] = p2.x; a[5] = p2.y;
    ulonglong2 p3 = *(const ulonglong2*)(cp + 6);
    ulonglong2 p4 = *(const ulonglong2*)(cp + 8);
    ulonglong2 p5 = *(const ulonglong2*)(cp + 10);
    b[0] = p3.x; b[1] = p3.y; b[2] = p4.x; b[3] = p4.y; b[4] = p5.x; b[5] = p5.y;
  }

  u64 s[10];
#pragma unroll
  for (int k = 0; k < 10; ++k) {
    u64 best = 0;
    if (k < 6) best = umax(a[k], b[k]);
#pragma unroll
    for (int i2 = 0; i2 < 6; ++i2) {
      const int j2 = k - 1 - i2;
      if (j2 >= 0 && j2 < 6) best = umax(best, umin(a[i2], b[j2]));
    }
    s[k] = best;
  }

#pragma unroll
  for (int msk = 1; msk < 64; msk <<= 1) {
    u64 t[10];
#pragma unroll
    for (int k = 0; k < 10; ++k) t[k] = __shfl_xor(s[k], msk);
    u64 r2[10];
#pragma unroll
    for (int k = 0; k < 10; ++k) {
      u64 best = umax(s[k], t[k]);
#pragma unroll
      for (int i2 = 0; i2 < 10; ++i2) {
        const int j2 = k - 1 - i2;
        if (j2 >= 0 && j2 < 10) best = umax(best, umin(s[i2], t[j2]));
      }
      r2[k] = best;
    }
#pragma unroll
    for (int k = 0; k < 10; ++k) s[k] = r2[k];
  }

  int cidx[NCAND];
#pragma unroll
  for (int c = 0; c < NCAND; ++c)
    cidx[c] = (int)(0xFFFFFFFFu - (unsigned)(s[c] & 0xFFFFFFFFull));

  const float* zrow = z + (size_t)row * DIM;
  const int d0 = lane * 8;
  const float4 za = *(const float4*)(zrow + d0);
  const float4 zb = *(const float4*)(zrow + d0 + 4);
  const float myz2 = g_z2[row];

  double p[NCAND];
#pragma unroll
  for (int c = 0; c < NCAND; ++c) {
    const float* cptr = centers + (size_t)cidx[c] * DIM + d0;
    float4 ca = *(const float4*)(cptr);
    float4 cb = *(const float4*)(cptr + 4);
    p[c] = (double)za.x * ca.x + (double)za.y * ca.y +
           (double)za.z * ca.z + (double)za.w * ca.w +
           (double)zb.x * cb.x + (double)zb.y * cb.y +
           (double)zb.z * cb.z + (double)zb.w * cb.w;
  }
#pragma unroll
  for (int off = 32; off > 0; off >>= 1) {
#pragma unroll
    for (int c = 0; c < NCAND; ++c) p[c] += __shfl_xor(p[c], off);
  }

  float exv[NCAND];
#pragma unroll
  for (int c = 0; c < NCAND; ++c) {
    const int ci = cidx[c];
    float dotf = (float)p[c];
    float t   = __fadd_rn(myz2, g_c2[ci]);
    float sq  = __fsub_rn(t, __fmul_rn(2.0f, dotf));
    float d   = sqrtf(fmaxf(sq, 0.0f));
    float den = __fadd_rn(__fmul_rn(d, d), 1e-6f);
    exv[c] = __fdiv_rn(mus[ci], den);
  }

  unsigned used = 0;
  float tv[KEXP]; int tix[KEXP];
#pragma unroll
  for (int s2 = 0; s2 < KEXP; ++s2) {
    float bv = -INFINITY; int bi = 0x7FFFFFFF; int bc = 0;
#pragma unroll
    for (int c = 0; c < NCAND; ++c) {
      bool ok = (used & (1u << c)) == 0;
      if (ok && (exv[c] > bv || (exv[c] == bv && cidx[c] < bi))) {
        bv = exv[c]; bi = cidx[c]; bc = c;
      }
    }
    used |= (1u << bc);
    tv[s2] = bv; tix[s2] = bi;
  }

  float mm = tv[0];
  float w[KEXP];
  float ssum = 0.0f;
#pragma unroll
  for (int kk = 0; kk < KEXP; ++kk) { w[kk] = expf(tv[kk] - mm); ssum += w[kk]; }
#pragma unroll
  for (int kk = 0; kk < KEXP; ++kk) w[kk] /= ssum;

  float comb[8] = {0, 0, 0, 0, 0, 0, 0, 0};
#pragma unroll
  for (int kk = 0; kk < KEXP; ++kk) {
    const float* cptr = centers + (size_t)tix[kk] * DIM + d0;
    float4 aq = *(const float4*)(cptr);
    float4 bq = *(const float4*)(cptr + 4);
    comb[0] += w[kk] * aq.x; comb[1] += w[kk] * aq.y;
    comb[2] += w[kk] * aq.z; comb[3] += w[kk] * aq.w;
    comb[4] += w[kk] * bq.x; comb[5] += w[kk] * bq.y;
    comb[6] += w[kk] * bq.z; comb[7] += w[kk] * bq.w;
  }
  const float zv[8] = {za.x, za.y, za.z, za.w, zb.x, zb.y, zb.z, zb.w};
  float o[8];
#pragma unroll
  for (int e = 0; e < 8; ++e)
    o[e] = __fadd_rn(__fmul_rn(0.7f, zv[e]), __fmul_rn(0.3f, comb[e]));
  *(float4*)(out + (size_t)row * DIM + d0)     = *(float4*)&o[0];
  *(float4*)(out + (size_t)row * DIM + d0 + 4) = *(float4*)&o[4];
}

// ---------------------------------------------------------------------------
extern "C" void kernel_launch(void* const* d_in, const int* in_sizes, int n_in,
                              void* d_out, int out_size, void* d_ws, size_t ws_size,
                              hipStream_t stream) {
  const float* z       = (const float*)d_in[0];
  const float* centers = (const float*)d_in[1];
  const float* mus     = (const float*)d_in[2];
  float* out      = (float*)d_out;
  float* expanded = out;
  float* att      = out + (size_t)BATCH * DIM;

  convert_kernel<<<(BATCH + NC) * DIM / (256 * 8), 256, 0, stream>>>(z, centers);
  attr_bf16<<<(BATCH / BM) * (NC / BN), 256, 0, stream>>>(mus, att);
  topk2<<<BATCH / 4, 256, 0, stream>>>(z, centers, mus, expanded);
}